// Round 1
// 1308.111 us; speedup vs baseline: 1.0095x; 1.0095x over previous
//
#include <hip/hip_runtime.h>

typedef __bf16 bf16;
typedef __bf16 bf16x8 __attribute__((ext_vector_type(8)));
typedef float f32x4 __attribute__((ext_vector_type(4)));
typedef float f32x16 __attribute__((ext_vector_type(16)));

#define L_SEQ   2048
#define D_MODEL 3072
#define N_HEADS 24
#define N1      21504   // QKV + 4D  (gemm1 N)
#define QKV_N   9216
#define CC      15360   // D + 4D    (gemm2 K / concat width)

// ---------------- workspace layout (bytes) ----------------
// m_buf   @ 0          : 9216 f32 (shift|scale|gate)
// x_mod   @ 36864      : 2048x3072 bf16   (LN+modulated, GEMM1 A)
// w1t     @ 12619776   : 21504x3072 bf16  (w1 transposed; later reused for w2t 3072x15360)
// hqkv    @ 144740352  : 2048x9216 bf16   (raw qkv; reused as f32 gemm2 partial p0)
// concat  @ 182489088  : 2048x15360 bf16  (attn | gelu(mlp)) = GEMM2 A
// q_r     @ 245403648  : 24x2048x128 bf16 (with k_r: reused as f32 gemm2 partial p1)
// k_r     @ 257986560  : 24x2048x128 bf16
// v_t     @ 270569472  : 24x128x2048 bf16 (V transposed per head)

__device__ __forceinline__ void async_cp16(const void* g, void* s) {
    __builtin_amdgcn_global_load_lds((const __attribute__((address_space(1))) void*)g,
                                     (__attribute__((address_space(3))) void*)s, 16, 0, 0);
}

// ---------------- modulation GEMV ----------------
__global__ __launch_bounds__(256) void mod_init_kernel(const float* __restrict__ b_mod, float* __restrict__ m) {
    int j = blockIdx.x * 256 + threadIdx.x;
    m[j] = b_mod[j];
}

__global__ __launch_bounds__(256) void mod_gemv_kernel(const float* __restrict__ vec,
                                                       const float* __restrict__ w_mod,
                                                       float* __restrict__ m) {
    int j  = blockIdx.x * 256 + threadIdx.x;
    int d0 = blockIdx.y * 256;
    __shared__ float sv[256];
    float x = vec[d0 + threadIdx.x];
    sv[threadIdx.x] = x / (1.f + __expf(-x));   // silu
    __syncthreads();
    float acc = 0.f;
    #pragma unroll 8
    for (int d = 0; d < 256; d++)
        acc += sv[d] * w_mod[(size_t)(d0 + d) * QKV_N + j];
    atomicAdd(&m[j], acc);
}

// ---------------- layernorm + modulation -> bf16 ----------------
__global__ __launch_bounds__(256) void ln_kernel(const float* __restrict__ x,
                                                 const float* __restrict__ m,
                                                 bf16* __restrict__ x_mod) {
    int l = blockIdx.x, tid = threadIdx.x;
    const float4* xr = (const float4*)(x + (size_t)l * D_MODEL);
    float4 v[3];
    float s = 0.f, ss = 0.f;
    #pragma unroll
    for (int p = 0; p < 3; p++) {
        v[p] = xr[p * 256 + tid];
        s  += v[p].x + v[p].y + v[p].z + v[p].w;
        ss += v[p].x * v[p].x + v[p].y * v[p].y + v[p].z * v[p].z + v[p].w * v[p].w;
    }
    #pragma unroll
    for (int off = 32; off; off >>= 1) { s += __shfl_xor(s, off); ss += __shfl_xor(ss, off); }
    __shared__ float rs[4], rss[4];
    int wave = tid >> 6, lane = tid & 63;
    if (lane == 0) { rs[wave] = s; rss[wave] = ss; }
    __syncthreads();
    s  = rs[0] + rs[1] + rs[2] + rs[3];
    ss = rss[0] + rss[1] + rss[2] + rss[3];
    float mu   = s * (1.f / D_MODEL);
    float var  = ss * (1.f / D_MODEL) - mu * mu;
    float rstd = rsqrtf(var + 1e-6f);
    #pragma unroll
    for (int p = 0; p < 3; p++) {
        int c = (p * 256 + tid) * 4;
        const float* ve = (const float*)&v[p];
        union { bf16 b[4]; uint2 u; } pk;
        #pragma unroll
        for (int e = 0; e < 4; e++) {
            float xn = (ve[e] - mu) * rstd;
            pk.b[e] = (bf16)((1.f + m[D_MODEL + c + e]) * xn + m[c + e]);
        }
        *(uint2*)(x_mod + (size_t)l * D_MODEL + c) = pk.u;
    }
}

// ---------------- transpose + f32->bf16 convert: in (R,C) f32 -> out (C,R) bf16 ----------------
__global__ __launch_bounds__(256) void tconv_kernel(const float* __restrict__ in, bf16* __restrict__ out,
                                                    int R, int C) {
    __shared__ float T[64][65];
    int c0 = blockIdx.x * 64, r0 = blockIdx.y * 64;
    int tid = threadIdx.x;
    int col4 = (tid & 15) * 4, rr = tid >> 4;
    #pragma unroll
    for (int p = 0; p < 4; p++) {
        int r = rr + p * 16;
        float4 v = *(const float4*)(in + (size_t)(r0 + r) * C + c0 + col4);
        T[r][col4 + 0] = v.x; T[r][col4 + 1] = v.y; T[r][col4 + 2] = v.z; T[r][col4 + 3] = v.w;
    }
    __syncthreads();
    int c = tid >> 2, rq = (tid & 3) * 16;
    union { bf16 b[16]; uint4 u[2]; } pk;
    #pragma unroll
    for (int i = 0; i < 16; i++) pk.b[i] = (bf16)T[rq + i][c];
    uint4* op = (uint4*)(out + (size_t)(c0 + c) * R + r0 + rq);
    op[0] = pk.u[0]; op[1] = pk.u[1];
}

// ================= 256x256 tile, BK=64, 8 waves, 8-phase schedule =================
// T2 (XOR-swizzled LDS via pre-swizzled global src) + T3/T4 (per-phase interleave,
// counted vmcnt, never 0 in steady state) + T5 (setprio around MFMA cluster).
// Per-wave C = two 64-row stripes (one per staged A-half) x two 32-col stripes
// (one per staged B-half), so phase quadrant (mh,nh) <-> staged half 1:1.
// Phase order (0,0),(0,1),(1,1),(1,0); half deaths: A0@P2, B1@P3, A1/B0@P4.
// Stage slots: P1->B0(t+1), P2->A1(t+1), P3->A0(t+2), P4->B1(t+2); vmcnt(4)@P4.
#define TILESZ 16384   // 256*64 bf16 elements per operand per buffer
#define BUFSZ  32768   // A + B

template <int EPI>
__global__ __launch_bounds__(512, 2) void gemm_kernel(
    const bf16* __restrict__ A, const bf16* __restrict__ Bt,
    const float* __restrict__ bias, int K, int ld,
    bf16* __restrict__ o_qkv, bf16* __restrict__ o_concat,
    float* __restrict__ p0, float* __restrict__ p1) {
    __shared__ bf16 lds[2 * BUFSZ];   // 128 KiB

    const int tid  = threadIdx.x;
    const int wave = tid >> 6, lane = tid & 63;
    const int mgrp = wave >> 2, ngrp = wave & 3;
    const int l15 = lane & 15, l4 = lane >> 4, l7 = lane & 7;

    // bijective XCD-chunked swizzle (gridDim.x==8 always; nwg % 8 == 0)
    const int flat = blockIdx.y * 8 + blockIdx.x;
    const int nwg  = gridDim.y * 8;
    const int swz  = (flat & 7) * (nwg >> 3) + (flat >> 3);
    const int m0 = (swz & 7) * 256;        // M fastest -> B panel reuse
    const int n0 = (swz >> 3) * 256;
    const int koff = (EPI == 2) ? blockIdx.z * K : 0;
    const int nt = K >> 6;

    // staging geometry: wave covers rows wave*8+srow of each 64-row call;
    // global chunk pre-swizzled so LDS chunk p of row r holds global chunk p^(r&7)
    const int srow   = lane >> 3;
    const int schunk = (lane & 7) ^ srow;
    const bf16* Ag = A  + (size_t)(m0 + wave * 8 + srow) * ld + koff + schunk * 8;
    const bf16* Bg = Bt + (size_t)(n0 + wave * 8 + srow) * ld + koff + schunk * 8;
    const size_t ld64  = (size_t)ld * 64;
    const size_t ld128 = (size_t)ld * 128;
    const int lw = wave * 8 * 64;          // wave-uniform LDS write base (elements)

#define STAGE_A(hh, tt, bb) { \
    const bf16* _g = Ag + (size_t)(hh) * ld128 + (size_t)(tt) * 64; \
    bf16* _l = lds + (bb) * BUFSZ + (hh) * 8192 + lw; \
    async_cp16(_g, _l); \
    async_cp16(_g + ld64, _l + 4096); }
#define STAGE_B(hh, tt, bb) { \
    const bf16* _g = Bg + (size_t)(hh) * ld128 + (size_t)(tt) * 64; \
    bf16* _l = lds + (bb) * BUFSZ + TILESZ + (hh) * 8192 + lw; \
    async_cp16(_g, _l); \
    async_cp16(_g + ld64, _l + 4096); }
// reader: global k-chunk g = kk*4 + l4 stored at position g^(row&7); row&7 == l7 here
#define LDA_H(mh, bb) { \
    const bf16* _p = lds + (bb) * BUFSZ + (mh) * 8192 + (mgrp * 64 + l15) * 64; \
    _Pragma("unroll") for (int i = 0; i < 4; i++) \
    _Pragma("unroll") for (int kk = 0; kk < 2; kk++) \
        aA[i][kk] = *(const bf16x8*)(_p + i * 1024 + ((kk * 4 + l4) ^ l7) * 8); }
#define LDB_H(nh, bb) { \
    const bf16* _p = lds + (bb) * BUFSZ + TILESZ + (nh) * 8192 + (ngrp * 32 + l15) * 64; \
    _Pragma("unroll") for (int j = 0; j < 2; j++) \
    _Pragma("unroll") for (int kk = 0; kk < 2; kk++) \
        bB[j][kk] = *(const bf16x8*)(_p + j * 1024 + ((kk * 4 + l4) ^ l7) * 8); }
#define MFMA_Q(mh, nh) { \
    __builtin_amdgcn_s_setprio(1); \
    _Pragma("unroll") for (int i = 0; i < 4; i++) \
    _Pragma("unroll") for (int j = 0; j < 2; j++) \
    _Pragma("unroll") for (int kk = 0; kk < 2; kk++) \
        acc[(mh) * 4 + i][(nh) * 2 + j] = __builtin_amdgcn_mfma_f32_16x16x32_bf16( \
            aA[i][kk], bB[j][kk], acc[(mh) * 4 + i][(nh) * 2 + j], 0, 0, 0); \
    __builtin_amdgcn_s_setprio(0); }
#define BAR()   __builtin_amdgcn_s_barrier()
#define LGKM0() asm volatile("s_waitcnt lgkmcnt(0)" ::: "memory")

    f32x4 acc[8][4];
    #pragma unroll
    for (int i = 0; i < 8; i++)
        #pragma unroll
        for (int j = 0; j < 4; j++)
            acc[i][j] = f32x4{0.f, 0.f, 0.f, 0.f};

    bf16x8 aA[4][2], bB[2][2];

    // prologue: tile0 complete (8 loads), then A0(1), B1(1) (the P3/P4 slots of "tile -1")
    STAGE_A(0, 0, 0); STAGE_A(1, 0, 0); STAGE_B(0, 0, 0); STAGE_B(1, 0, 0);
    if (nt > 1) {
        STAGE_A(0, 1, 1); STAGE_B(1, 1, 1);
        asm volatile("s_waitcnt vmcnt(4)" ::: "memory");
    } else {
        asm volatile("s_waitcnt vmcnt(0)" ::: "memory");
    }
    BAR();

    for (int u = 0; u < nt; ++u) {
        const int b = u & 1;
        // ---- phase 1: quadrant (0,0) ----
        LDA_H(0, b); LDB_H(0, b);                 // 12 ds_read_b128
        if (u + 1 < nt) STAGE_B(0, u + 1, b ^ 1); // B0(u+1): region dead since P4(u-1)
        BAR(); LGKM0();
        MFMA_Q(0, 0);
        BAR();
        // ---- phase 2: quadrant (0,1) ----
        LDB_H(1, b);                              // 4 reads (A-half reused)
        if (u + 1 < nt) STAGE_A(1, u + 1, b ^ 1);
        BAR(); LGKM0();
        MFMA_Q(0, 1);
        BAR();
        // ---- phase 3: quadrant (1,1) ----
        LDA_H(1, b);                              // 8 reads (B-half reused)
        if (u + 2 < nt) STAGE_A(0, u + 2, b);     // A0(u) died at P2
        BAR(); LGKM0();
        MFMA_Q(1, 1);
        BAR();
        // ---- phase 4: quadrant (1,0) ----
        LDB_H(0, b);                              // 4 reads (reload B0)
        if (u + 2 < nt) STAGE_B(1, u + 2, b);     // B1(u) died at P3
        if (u + 1 < nt) {
            if (u + 2 < nt) asm volatile("s_waitcnt vmcnt(4)" ::: "memory"); // keep A0/B1(u+2) in flight
            else            asm volatile("s_waitcnt vmcnt(0)" ::: "memory"); // tail drain
        }
        BAR(); LGKM0();
        MFMA_Q(1, 0);
        BAR();
    }

    // C/D (16x16): col = lane&15, row = (lane>>4)*4 + reg
    float* po = (EPI == 2) ? (blockIdx.z ? p1 : p0) : nullptr;
    #pragma unroll
    for (int mh = 0; mh < 2; mh++)
    #pragma unroll
    for (int i = 0; i < 4; i++) {
        const int rbase = m0 + mh * 128 + mgrp * 64 + i * 16 + l4 * 4;
        #pragma unroll
        for (int nh = 0; nh < 2; nh++)
        #pragma unroll
        for (int j = 0; j < 2; j++) {
            const int col = n0 + nh * 128 + ngrp * 32 + j * 16 + l15;
            f32x4 v4 = acc[mh * 4 + i][nh * 2 + j];
            if (EPI == 1) {
                const float bv = bias[col];
                if (col < QKV_N) {
                    #pragma unroll
                    for (int r = 0; r < 4; r++)
                        o_qkv[(size_t)(rbase + r) * QKV_N + col] = (bf16)(v4[r] + bv);
                } else {
                    #pragma unroll
                    for (int r = 0; r < 4; r++) {
                        float v = v4[r] + bv;
                        float g = 0.5f * v * (1.f + tanhf(0.7978845608028654f * (v + 0.044715f * v * v * v)));
                        o_concat[(size_t)(rbase + r) * CC + (col - QKV_N + D_MODEL)] = (bf16)g;
                    }
                }
            } else {
                #pragma unroll
                for (int r = 0; r < 4; r++)
                    po[(size_t)(rbase + r) * D_MODEL + col] = v4[r];
            }
        }
    }
#undef STAGE_A
#undef STAGE_B
#undef LDA_H
#undef LDB_H
#undef MFMA_Q
#undef BAR
#undef LGKM0
}

// ---------------- final residual epilogue: out = x + gate*(p0+p1+b2) ----------------
__global__ __launch_bounds__(256) void res_kernel(const float* __restrict__ p0, const float* __restrict__ p1,
                                                  const float* __restrict__ x, const float* __restrict__ gate,
                                                  const float* __restrict__ b2, float* __restrict__ out) {
    int i = blockIdx.x * 256 + threadIdx.x;
    float4 a  = ((const float4*)p0)[i];
    float4 b  = ((const float4*)p1)[i];
    float4 xr = ((const float4*)x)[i];
    int col = (i * 4) % D_MODEL;
    float4 g  = *(const float4*)(gate + col);
    float4 bb = *(const float4*)(b2 + col);
    float4 o;
    o.x = xr.x + g.x * (a.x + b.x + bb.x);
    o.y = xr.y + g.y * (a.y + b.y + bb.y);
    o.z = xr.z + g.z * (a.z + b.z + bb.z);
    o.w = xr.w + g.w * (a.w + b.w + bb.w);
    ((float4*)out)[i] = o;
}

// ---------------- RMSNorm + RoPE for q,k: one wave per (l,head) row ----------------
__global__ __launch_bounds__(256) void qkv_rope_kernel(const bf16* __restrict__ hqkv,
                                                       const float* __restrict__ pe,
                                                       const float* __restrict__ q_scale,
                                                       const float* __restrict__ k_scale,
                                                       bf16* __restrict__ q_r, bf16* __restrict__ k_r) {
    int wave = threadIdx.x >> 6, lane = threadIdx.x & 63;
    int idx = blockIdx.x * 4 + wave;          // 0 .. 2048*24-1
    int l = idx / N_HEADS, h = idx - l * N_HEADS;
    const bf16* qg = hqkv + (size_t)l * QKV_N + h * 128;
    const bf16* kg = qg + D_MODEL;
    float q0 = (float)qg[2 * lane], q1 = (float)qg[2 * lane + 1];
    float k0 = (float)kg[2 * lane], k1 = (float)kg[2 * lane + 1];
    float sq = q0 * q0 + q1 * q1, sk = k0 * k0 + k1 * k1;
    #pragma unroll
    for (int off = 32; off; off >>= 1) { sq += __shfl_xor(sq, off); sk += __shfl_xor(sk, off); }
    float rq = rsqrtf(sq * (1.f / 128.f) + 1e-6f);
    float rk = rsqrtf(sk * (1.f / 128.f) + 1e-6f);
    float s0 = q_scale[2 * lane], s1 = q_scale[2 * lane + 1];
    float z0 = k_scale[2 * lane], z1 = k_scale[2 * lane + 1];
    float4 p = ((const float4*)pe)[(size_t)l * 64 + lane];
    float tq0 = q0 * rq * s0, tq1 = q1 * rq * s1;
    float tk0 = k0 * rk * z0, tk1 = k1 * rk * z1;
    size_t ob = ((size_t)h * L_SEQ + l) * 128 + 2 * lane;
    q_r[ob]     = (bf16)(p.x * tq0 + p.y * tq1);
    q_r[ob + 1] = (bf16)(p.z * tq0 + p.w * tq1);
    k_r[ob]     = (bf16)(p.x * tk0 + p.y * tk1);
    k_r[ob + 1] = (bf16)(p.z * tk0 + p.w * tk1);
}

// ---------------- V transpose: hqkv v-part (l, h*128+d) -> v_t (h, d, l) ----------------
__global__ __launch_bounds__(256) void vtrans_kernel(const bf16* __restrict__ hqkv, bf16* __restrict__ v_t) {
    int dt = blockIdx.x * 64, lt = blockIdx.y * 64, h = blockIdx.z;
    __shared__ bf16 T[64][72];
    int tid = threadIdx.x;
    #pragma unroll
    for (int p = 0; p < 2; p++) {
        int idx = p * 256 + tid;
        int r = idx >> 3, c = idx & 7;
        uint4 v = *(const uint4*)(hqkv + (size_t)(lt + r) * QKV_N + 2 * D_MODEL + h * 128 + dt + c * 8);
        *(uint4*)(&T[r][c * 8]) = v;
    }
    __syncthreads();
    #pragma unroll
    for (int p = 0; p < 2; p++) {
        int idx = p * 256 + tid;
        int d = idx >> 3, c = idx & 7;
        union { bf16 b[8]; uint4 u; } pk;
        #pragma unroll
        for (int i = 0; i < 8; i++) pk.b[i] = T[c * 8 + i][d];
        *(uint4*)(v_t + ((size_t)h * 128 + dt + d) * L_SEQ + lt + c * 8) = pk.u;
    }
}

// ---------------- flash attention: one block per (head, 64 q rows); Q in registers ----------------
#define QK_LD 136
#define VP_LD 72
__global__ __launch_bounds__(256) void attn_kernel(const bf16* __restrict__ q_r, const bf16* __restrict__ k_r,
                                                   const bf16* __restrict__ v_t, bf16* __restrict__ concat) {
    const int h = blockIdx.y;
    const int q0 = blockIdx.x * 64;
    __shared__ bf16 Ks[64 * QK_LD];
    __shared__ bf16 Vs[128 * VP_LD];   // V^T tile: [d][key]
    __shared__ bf16 Ps[64 * VP_LD];
    const int tid = threadIdx.x, wave = tid >> 6, lane = tid & 63;
    const int l16 = lane & 15, lq = lane >> 4;
    const bf16* Qg = q_r + ((size_t)h * L_SEQ + q0) * 128;
    const bf16* Kg = k_r + (size_t)h * L_SEQ * 128;
    const bf16* Vg = v_t + (size_t)h * 128 * L_SEQ;
    bf16x8 aq[4];
    #pragma unroll
    for (int kk = 0; kk < 4; kk++)
        aq[kk] = *(const bf16x8*)(Qg + (size_t)(wave * 16 + l16) * 128 + kk * 32 + lq * 8);
    f32x4 accO[8];
    #pragma unroll
    for (int i = 0; i < 8; i++) accO[i] = f32x4{0.f, 0.f, 0.f, 0.f};
    float mrow[4] = {-1e30f, -1e30f, -1e30f, -1e30f};
    float lrow[4] = {0.f, 0.f, 0.f, 0.f};
    const float sc = 0.08838834764831845f * 1.4426950408889634f;   // 128^-0.5 * log2(e)
    for (int kt = 0; kt < 32; kt++) {
        __syncthreads();
        const bf16* Kt = Kg + (size_t)kt * 64 * 128;
        const bf16* Vt = Vg + kt * 64;
        #pragma unroll
        for (int p = 0; p < 4; p++) {
            int idx = p * 256 + tid, r = idx >> 4, c = idx & 15;
            *(uint4*)(Ks + r * QK_LD + c * 8) = *(const uint4*)(Kt + (size_t)r * 128 + c * 8);
        }
        #pragma unroll
        for (int p = 0; p < 4; p++) {
            int idx = p * 256 + tid, r = idx >> 3, c = idx & 7;
            *(uint4*)(Vs + r * VP_LD + c * 8) = *(const uint4*)(Vt + (size_t)r * L_SEQ + c * 8);
        }
        __syncthreads();
        f32x4 accS[4];
        #pragma unroll
        for (int i = 0; i < 4; i++) accS[i] = f32x4{0.f, 0.f, 0.f, 0.f};
        #pragma unroll
        for (int kk = 0; kk < 4; kk++) {
            #pragma unroll
            for (int nt = 0; nt < 4; nt++) {
                bf16x8 b = *(const bf16x8*)(Ks + (nt * 16 + l16) * QK_LD + kk * 32 + lq * 8);
                accS[nt] = __builtin_amdgcn_mfma_f32_16x16x32_bf16(aq[kk], b, accS[nt], 0, 0, 0);
            }
        }
        float alpha[4];
        #pragma unroll
        for (int r = 0; r < 4; r++) {
            float x0 = accS[0][r] * sc, x1 = accS[1][r] * sc, x2 = accS[2][r] * sc, x3 = accS[3][r] * sc;
            float mx = fmaxf(fmaxf(x0, x1), fmaxf(x2, x3));
            #pragma unroll
            for (int off = 1; off < 16; off <<= 1) mx = fmaxf(mx, __shfl_xor(mx, off));
            float mnew = fmaxf(mrow[r], mx);
            alpha[r] = __builtin_amdgcn_exp2f(mrow[r] - mnew);
            float p0 = __builtin_amdgcn_exp2f(x0 - mnew), p1 = __builtin_amdgcn_exp2f(x1 - mnew);
            float p2 = __builtin_amdgcn_exp2f(x2 - mnew), p3 = __builtin_amdgcn_exp2f(x3 - mnew);
            float rsum = p0 + p1 + p2 + p3;
            #pragma unroll
            for (int off = 1; off < 16; off <<= 1) rsum += __shfl_xor(rsum, off);
            lrow[r] = lrow[r] * alpha[r] + rsum;
            mrow[r] = mnew;
            int prow = wave * 16 + lq * 4 + r;
            Ps[prow * VP_LD +  0 + l16] = (bf16)p0;
            Ps[prow * VP_LD + 16 + l16] = (bf16)p1;
            Ps[prow * VP_LD + 32 + l16] = (bf16)p2;
            Ps[prow * VP_LD + 48 + l16] = (bf16)p3;
        }
        #pragma unroll
        for (int i = 0; i < 8; i++) {
            accO[i][0] *= alpha[0]; accO[i][1] *= alpha[1];
            accO[i][2] *= alpha[2]; accO[i][3] *= alpha[3];
        }
        #pragma unroll
        for (int kk = 0; kk < 2; kk++) {
            bf16x8 a = *(const bf16x8*)(Ps + (wave * 16 + l16) * VP_LD + kk * 32 + lq * 8);
            #pragma unroll
            for (int nt = 0; nt < 8; nt++) {
                bf16x8 b = *(const bf16x8*)(Vs + (nt * 16 + l16) * VP_LD + kk * 32 + lq * 8);
                accO[nt] = __builtin_amdgcn_mfma_f32_16x16x32_bf16(a, b, accO[nt], 0, 0, 0);
            }
        }
    }
    float inv[4];
    #pragma unroll
    for (int r = 0; r < 4; r++) inv[r] = 1.f / lrow[r];
    #pragma unroll
    for (int nt = 0; nt < 8; nt++)
        #pragma unroll
        for (int r = 0; r < 4; r++) {
            int row = q0 + wave * 16 + lq * 4 + r;
            concat[(size_t)row * CC + h * 128 + nt * 16 + l16] = (bf16)(accO[nt][r] * inv[r]);
        }
}

// ---------------- launch ----------------
extern "C" void kernel_launch(void* const* d_in, const int* in_sizes, int n_in,
                              void* d_out, int out_size, void* d_ws, size_t ws_size,
                              hipStream_t stream) {
    const float* x       = (const float*)d_in[0];
    const float* vec     = (const float*)d_in[1];
    const float* pe      = (const float*)d_in[2];
    const float* w_mod   = (const float*)d_in[3];
    const float* b_mod   = (const float*)d_in[4];
    const float* w1      = (const float*)d_in[5];
    const float* b1      = (const float*)d_in[6];
    const float* w2      = (const float*)d_in[7];
    const float* b2      = (const float*)d_in[8];
    const float* q_scale = (const float*)d_in[9];
    const float* k_scale = (const float*)d_in[10];
    float* out = (float*)d_out;

    char* ws = (char*)d_ws;
    float* m_buf  = (float*)(ws);
    bf16* x_mod   = (bf16*)(ws + 36864);
    bf16* w1t     = (bf16*)(ws + 12619776);    // reused for w2t after gemm1
    bf16* hqkv    = (bf16*)(ws + 144740352);
    bf16* concat  = (bf16*)(ws + 182489088);
    bf16* q_r     = (bf16*)(ws + 245403648);
    bf16* k_r     = (bf16*)(ws + 257986560);
    bf16* v_t     = (bf16*)(ws + 270569472);
    float* p0     = (float*)(ws + 144740352);  // aliases hqkv (dead after attn inputs built)
    float* p1     = (float*)(ws + 245403648);  // aliases q_r+k_r (dead after attn)

    mod_init_kernel<<<36, 256, 0, stream>>>(b_mod, m_buf);
    mod_gemv_kernel<<<dim3(36, 12), 256, 0, stream>>>(vec, w_mod, m_buf);
    ln_kernel<<<L_SEQ, 256, 0, stream>>>(x, m_buf, x_mod);
    tconv_kernel<<<dim3(N1 / 64, D_MODEL / 64), 256, 0, stream>>>(w1, w1t, D_MODEL, N1);
    // grid.x = M tiles (8), grid.y = N tiles
    gemm_kernel<1><<<dim3(L_SEQ / 256, N1 / 256, 1), 512, 0, stream>>>(
        x_mod, w1t, b1, D_MODEL, D_MODEL, hqkv, concat, nullptr, nullptr);
    qkv_rope_kernel<<<L_SEQ * N_HEADS / 4, 256, 0, stream>>>(hqkv, pe, q_scale, k_scale, q_r, k_r);
    vtrans_kernel<<<dim3(2, 32, N_HEADS), 256, 0, stream>>>(hqkv, v_t);
    attn_kernel<<<dim3(32, N_HEADS), 256, 0, stream>>>(q_r, k_r, v_t, concat);
    tconv_kernel<<<dim3(D_MODEL / 64, CC / 64), 256, 0, stream>>>(w2, w1t, CC, D_MODEL);
    gemm_kernel<2><<<dim3(L_SEQ / 256, D_MODEL / 256, 2), 512, 0, stream>>>(
        concat, w1t, nullptr, CC / 2, CC, nullptr, nullptr, p0, p1);
    res_kernel<<<L_SEQ * D_MODEL / 1024, 256, 0, stream>>>(p0, p1, x, m_buf + 2 * D_MODEL, b2, out);
}